// Round 7
// baseline (185.191 us; speedup 1.0000x reference)
//
#include <hip/hip_runtime.h>
#include <hip/hip_bf16.h>
#include <stdint.h>

#define E_IN_N   1048576
#define E_OUT_N  131072
#define KTAPS    9
#define CIN      64
#define COUT     64
#define NCELL    (E_OUT_N*KTAPS)   /* 1179648 */
#define NB_SCAN  1152              /* NCELL/1024 */
#define TILE_E   32
#define NKSTEP   18                /* 576/32 */
#define CHUNK    32

typedef __attribute__((ext_vector_type(8))) short bf16x8;
typedef __attribute__((ext_vector_type(4))) float f32x4;

__device__ __forceinline__ ushort f32_bf16(float x){
  union{float f; uint32_t u;} v; v.f=x;
  uint32_t r = v.u + 0x7FFFu + ((v.u>>16)&1u);
  return (ushort)(r>>16);
}

// fused: zero counts (blocks 0..1151: 1152*256 int4 = NCELL ints) + W pre-permute (1152..1295)
__global__ void prep_k(int* __restrict__ counts, const float* __restrict__ wk,
                       ushort* __restrict__ wb){
  int b=blockIdx.x, t=threadIdx.x;
  if(b<1152){
    ((int4*)counts)[b*256+t]=int4{0,0,0,0};
  }else{
    int slot=(b-1152)*256+t;                 // 36864 total
    int j=slot&7; int t2=slot>>3; int lane=t2&63; int t3=t2>>6;
    int ks=t3%NKSTEP; int nt=t3/NKSTEP;
    int r=ks*32+((lane>>4)*8)+j; int col=nt*16+(lane&15);
    wb[slot]=f32_bf16(wk[r*COUT+col]);
  }
}

// histogram + per-event rank; cellrank = cell<<11 | rank  (cell<2^21, rank<2048)
__global__ void hist_k(const int* __restrict__ seg, const int* __restrict__ succ,
                       int* __restrict__ counts, uint32_t* __restrict__ cellrank){
  int i = blockIdx.x*256 + threadIdx.x;
  uint32_t cell = (uint32_t)(seg[i]*KTAPS + succ[i]);
  uint32_t rank = (uint32_t)atomicAdd(&counts[cell],1);
  cellrank[i] = (cell<<11) | rank;
}

__global__ void blocksum_k(const int* __restrict__ counts, int* __restrict__ bsum){
  __shared__ int sm[256];
  int b=blockIdx.x, t=threadIdx.x;
  const int4 c4 = *(const int4*)(counts + b*1024 + t*4);
  int s=c4.x+c4.y+c4.z+c4.w;
  sm[t]=s; __syncthreads();
  for(int d=128; d>0; d>>=1){ if(t<d) sm[t]+=sm[t+d]; __syncthreads(); }
  if(t==0) bsum[b]=sm[0];
}

// fused: block prefix over bsum + intra-block scan of counts -> offsets
__global__ void offsets_k(const int* __restrict__ counts, const int* __restrict__ bsum,
                          int* __restrict__ offsets){
  __shared__ int sm[256];
  int b=blockIdx.x, t=threadIdx.x;
  int s=0;
  for(int j=t; j<NB_SCAN; j+=256) if(j<b) s+=bsum[j];
  sm[t]=s; __syncthreads();
  for(int d=128; d>0; d>>=1){ if(t<d) sm[t]+=sm[t+d]; __syncthreads(); }
  int base0=sm[0]; __syncthreads();
  int base=b*1024+t*4;
  const int4 c4=*(const int4*)(counts+base);
  int s2=c4.x+c4.y+c4.z+c4.w;
  sm[t]=s2; __syncthreads();
  for(int d=1; d<256; d<<=1){ int x=(t>=d)?sm[t-d]:0; __syncthreads(); sm[t]+=x; __syncthreads(); }
  int e0v=base0 + ((t==0)?0:sm[t-1]);
  int4 o; o.x=e0v; o.y=e0v+c4.x; o.z=o.y+c4.y; o.w=o.z+c4.z;
  *(int4*)(offsets+base)=o;
  if(b==NB_SCAN-1 && t==255) offsets[NCELL]=o.w+c4.w;
}

// place events: pos = offsets[cell] + rank (no atomics); payload = idx|(cell%288)<<20, dt
__global__ void scatter_k(const uint32_t* __restrict__ cellrank, const float* __restrict__ dtv,
                          const int* __restrict__ offsets, int2* __restrict__ sorted2){
  int i=blockIdx.x*256+threadIdx.x;
  uint32_t cr=cellrank[i];
  uint32_t cell=cr>>11, rank=cr&2047u;
  int base=offsets[cell];
  float d=dtv[i];
  uint32_t x=cell>>5;
  uint32_t q=__umulhi(x,477218592u);          // /9  (exact for x<2^27)
  uint32_t rel=cell - q*288u;                 // cell % 288 (block-local)
  sorted2[base+(int)rank]=int2{(int)((uint32_t)i | (rel<<20)), __float_as_int(d)};
}

__global__ __launch_bounds__(512,4) void compute_k(
    const float* __restrict__ features, const float* __restrict__ decay,
    const float* __restrict__ bias, const int* __restrict__ offsets,
    const int2* __restrict__ sorted2, const ushort* __restrict__ wb,
    float* __restrict__ out)
{
  __shared__ ushort agg[TILE_E*584];   // 576 + 8 pad per row
  const int tid=threadIdx.x, wv=tid>>6, lane=tid&63;
  const int e0=blockIdx.x*TILE_E;
  const int cb0=e0*KTAPS;

  for(int i=tid;i<TILE_E*584/2;i+=512) ((uint32_t*)agg)[i]=0u;
  float x=decay[lane];
  float rate=fmaxf(x,0.f)+log1pf(__expf(-fabsf(x)));   // softplus
  __syncthreads();

  // ---- aggregation: wave owns 36 contiguous cells (rel in [wv*36, wv*36+36)) ----
  // 32-event branchless chunks: scalar payload loads, 32 gathers in flight,
  // last-write-wins per-cell merge (same-cell events are contiguous).
  {
    const int c0=cb0+wv*36;
    int jv=0; if(lane<2) jv=offsets[c0+lane*36];
    int cb = __builtin_amdgcn_readfirstlane(__shfl(jv,0));
    const int jE = __builtin_amdgcn_readfirstlane(__shfl(jv,1));

    int prevRel=-1;
    float num=0.f, den=1.f;

    while(cb<jE){
      int qx[CHUNK]; float qd[CHUNK];
      #pragma unroll
      for(int e=0;e<CHUNK;e++){            // uniform base -> scalar loads
        int2 t=sorted2[cb+e];
        qx[e]=t.x; qd[e]=__int_as_float(t.y);
      }
      float fl[CHUNK];
      #pragma unroll
      for(int e=0;e<CHUNK;e++){            // 32 independent gathers in flight
        int iu = qx[e] & 0xFFFFF;          // idx < 2^20 == E_IN, always in-bounds
        fl[e] = features[((size_t)iu<<6) + lane];
      }
      #pragma unroll
      for(int e=0;e<CHUNK;e++){
        const int ok = (cb+e) < jE;        // scalar
        int rel = (int)(((uint32_t)qx[e])>>20);
        rel = ok ? rel : prevRel;          // pad: repeat last cell (harmless rewrite)
        float w = __expf(-qd[e]*rate);
        w = ok ? w : 0.f;                  // select AFTER exp: kills inf/NaN from pad garbage
        const float same = (rel==prevRel) ? 1.f : 0.f;
        num = num*same + w*fl[e];
        den = den*same + w;
        const int le=(rel*7282)>>16, kk=rel-le*9;
        agg[le*584 + kk*64 + lane] = f32_bf16(num*__builtin_amdgcn_rcpf(den));
        prevRel = rel;
      }
      cb += CHUNK;
    }
  }
  __syncthreads();

  // ---- GEMM: wave tile = 16 rows (mt) x 16 cols (nt), K=576 ----
  const int mt=wv>>2, nt=wv&3;
  const int arow=mt*16+(lane&15);
  const int koff=(lane>>4)*8;
  const ushort* wbp = wb + ((size_t)(nt*NKSTEP)*64 + (size_t)lane)*8;
  f32x4 acc={0.f,0.f,0.f,0.f};
  #pragma unroll
  for(int ks=0;ks<NKSTEP;ks++){
    bf16x8 a=*(const bf16x8*)&agg[arow*584+ks*32+koff];
    bf16x8 bfr=*(const bf16x8*)(wbp + (size_t)ks*512);
    acc=__builtin_amdgcn_mfma_f32_16x16x32_bf16(a,bfr,acc,0,0,0);
  }
  const int orow=e0+mt*16+((lane>>4)*4);
  const int ocol=nt*16+(lane&15);
  const float bv=bias[ocol];
  #pragma unroll
  for(int r=0;r<4;r++) out[(size_t)(orow+r)*COUT+ocol]=acc[r]+bv;
}

extern "C" void kernel_launch(void* const* d_in, const int* in_sizes, int n_in,
                              void* d_out, int out_size, void* d_ws, size_t ws_size,
                              hipStream_t stream){
  const float* features=(const float*)d_in[0];
  const float* dtv=(const float*)d_in[1];
  const float* decay=(const float*)d_in[3];
  const float* wk=(const float*)d_in[4];
  const float* bias=(const float*)d_in[5];
  const int* succ=(const int*)d_in[6];
  const int* seg=(const int*)d_in[7];

  char* ws=(char*)d_ws;
  size_t o=0;
  int* counts=(int*)(ws+o);      o+=(size_t)NCELL*4;
  int* offsets=(int*)(ws+o);     o+=(size_t)(NCELL+4)*4;
  int* bsum=(int*)(ws+o);        o+=(size_t)NB_SCAN*4;
  uint32_t* cellrank=(uint32_t*)(ws+o); o+=(size_t)E_IN_N*4;
  int2* sorted2=(int2*)(ws+o);   o+=(size_t)(E_IN_N+CHUNK)*8;  // slack for padded chunk reads
  ushort* wb=(ushort*)(ws+o);    o+=(size_t)36864*2;
  float* out=(float*)d_out;

  hipLaunchKernelGGL(prep_k, dim3(1296),dim3(256),0,stream, counts,wk,wb);
  hipLaunchKernelGGL(hist_k, dim3(E_IN_N/256),dim3(256),0,stream, seg,succ,counts,cellrank);
  hipLaunchKernelGGL(blocksum_k, dim3(NB_SCAN),dim3(256),0,stream, counts,bsum);
  hipLaunchKernelGGL(offsets_k, dim3(NB_SCAN),dim3(256),0,stream, counts,bsum,offsets);
  hipLaunchKernelGGL(scatter_k, dim3(E_IN_N/256),dim3(256),0,stream, cellrank,dtv,offsets,sorted2);
  hipLaunchKernelGGL(compute_k, dim3(E_OUT_N/TILE_E),dim3(512),0,stream,
                     features,decay,bias,offsets,sorted2,wb,out);
}